// Round 8
// baseline (151.693 us; speedup 1.0000x reference)
//
#include <hip/hip_runtime.h>

// Problem constants (from reference)
#define N_NODES 50000
#define N_EDGES 800000
#define IN_CH   128
#define HID_CH  128
#define OUT_CH  64

#define SCAN_B  1024
#define NB ((N_NODES + SCAN_B - 1) / SCAN_B)   // 49

typedef __attribute__((ext_vector_type(8))) short v8s;
typedef __attribute__((ext_vector_type(4))) float v4f;

// ---------------------------------------------------------------------------
// bf16 helpers (RNE)
__device__ __forceinline__ unsigned bf16rne(float f) {
  unsigned u = __float_as_uint(f);
  return (u + 0x7fffu + ((u >> 16) & 1u)) >> 16;
}
__device__ __forceinline__ unsigned pack2bf(float a, float b) {
  return bf16rne(a) | (bf16rne(b) << 16);
}
__device__ __forceinline__ float bfhi_to_f(unsigned u) {   // high ushort
  return __uint_as_float(u & 0xffff0000u);
}
__device__ __forceinline__ float bflo_to_f(unsigned u) {   // low ushort
  return __uint_as_float(u << 16);
}

// ---------------------------------------------------------------------------
// Init: zero deg[] (blocks 0-48) + convert both weight matrices (blocks 49+)
__global__ __launch_bounds__(256) void init_kernel(
    int* __restrict__ deg,
    const float* __restrict__ W1, const float* __restrict__ W2,
    unsigned short* __restrict__ Wt1, unsigned short* __restrict__ Wt2) {
  int b = blockIdx.x;
  if (b < 49) {
    int i = b * 256 + threadIdx.x;
    if (i < 50048 / 4) *(uint4*)&deg[i * 4] = make_uint4(0u, 0u, 0u, 0u);
  } else {
    int idx = (b - 49) * 256 + threadIdx.x;
    if (idx < 128 * 128) {
      int k = idx >> 7, c = idx & 127;
      Wt1[c * 128 + k] = (unsigned short)bf16rne(W1[idx]);
    } else if (idx < 128 * 128 + 128 * 64) {
      int i2 = idx - 128 * 128;
      int k = i2 >> 6, c = i2 & 63;
      Wt2[c * 128 + k] = (unsigned short)bf16rne(W2[i2]);
    }
  }
}

// CSR build step 1: degree histogram over dst; atomic return value IS the rank
__global__ __launch_bounds__(256) void hist_kernel(
    const int* __restrict__ dst, int* __restrict__ deg, int* __restrict__ rank) {
  int e = blockIdx.x * 256 + threadIdx.x;
  if (e < N_EDGES) rank[e] = atomicAdd(&deg[dst[e]], 1);
}

// CSR build step 2a: per-chunk sums + dinv (fused; both read deg)
__global__ __launch_bounds__(SCAN_B) void scan_partial_kernel(
    const int* __restrict__ deg, int* __restrict__ bsums, float* __restrict__ dinv) {
  __shared__ int sh[SCAN_B];
  int t = threadIdx.x;
  int g = blockIdx.x * SCAN_B + t;
  int v = (g < N_NODES) ? deg[g] : 0;
  sh[t] = v;
  if (g < N_NODES) dinv[g] = rsqrtf((float)v + 1.0f);
  __syncthreads();
  for (int off = SCAN_B / 2; off > 0; off >>= 1) {
    if (t < off) sh[t] += sh[t + off];
    __syncthreads();
  }
  if (t == 0) bsums[blockIdx.x] = sh[0];
}

// CSR build step 2b: per-chunk exclusive scan; block offset computed inline
// from raw bsums via a wave reduce (NB=49 <= 64 lanes).
__global__ __launch_bounds__(SCAN_B) void scan_final_kernel(
    const int* __restrict__ deg, const int* __restrict__ bsums,
    int* __restrict__ row_ptr) {
  __shared__ int sh[SCAN_B];
  __shared__ int s_off;
  int t = threadIdx.x;
  int g = blockIdx.x * SCAN_B + t;
  int v = (g < N_NODES) ? deg[g] : 0;
  sh[t] = v;
  if (t < 64) {
    int pv = (t < blockIdx.x && t < NB) ? bsums[t] : 0;
#pragma unroll
    for (int off = 32; off > 0; off >>= 1) pv += __shfl_down(pv, off);
    if (t == 0) s_off = pv;
  }
  if (g == 0) row_ptr[N_NODES] = N_EDGES;
  __syncthreads();
  for (int off = 1; off < SCAN_B; off <<= 1) {
    int add = (t >= off) ? sh[t - off] : 0;
    __syncthreads();
    sh[t] += add;
    __syncthreads();
  }
  int excl = sh[t] - v + s_off;
  if (g < N_NODES) row_ptr[g] = excl;
}

// CSR build step 3: place src ids (atomic-free; rank precomputed in hist)
__global__ __launch_bounds__(256) void place_kernel(
    const int* __restrict__ src, const int* __restrict__ dst,
    const int* __restrict__ rank, const int* __restrict__ row_ptr,
    int* __restrict__ csr_src) {
  int e = blockIdx.x * 256 + threadIdx.x;
  if (e < N_EDGES) {
    csr_src[row_ptr[dst[e]] + rank[e]] = src[e];
  }
}

// ---------------------------------------------------------------------------
// MFMA GEMM (layer 1): out[nrows x N] bf16 = A[nrows x 128] @ Bt^T.
// A is fp32 (converted during LDS staging).
template <int N, bool AFP32>
__global__ __launch_bounds__(256) void gemm_mfma_kernel(
    const void* __restrict__ Av, const unsigned short* __restrict__ Bt,
    unsigned short* __restrict__ out, int nrows) {
  constexpr int KP = 136;
  __shared__ unsigned short sA[64 * KP];
  __shared__ unsigned short sB[N * KP];

  const int row0 = blockIdx.x * 64;
  const int t = threadIdx.x;

  for (int i = t; i < 64 * 16; i += 256) {
    int r = i >> 4, ch = i & 15;
    uint4 v = make_uint4(0u, 0u, 0u, 0u);
    if (row0 + r < nrows) {
      if constexpr (AFP32) {
        const float* A = (const float*)Av;
        float4 f0 = *(const float4*)&A[(long)(row0 + r) * 128 + ch * 8];
        float4 f1 = *(const float4*)&A[(long)(row0 + r) * 128 + ch * 8 + 4];
        v.x = pack2bf(f0.x, f0.y); v.y = pack2bf(f0.z, f0.w);
        v.z = pack2bf(f1.x, f1.y); v.w = pack2bf(f1.z, f1.w);
      } else {
        const unsigned short* A = (const unsigned short*)Av;
        v = *(const uint4*)&A[(long)(row0 + r) * 128 + ch * 8];
      }
    }
    *(uint4*)&sA[r * KP + ch * 8] = v;
  }
  for (int i = t; i < N * 16; i += 256) {
    int r = i >> 4, ch = i & 15;
    *(uint4*)&sB[r * KP + ch * 8] = *(const uint4*)&Bt[(long)r * 128 + ch * 8];
  }
  __syncthreads();

  const int wave = t >> 6, lane = t & 63;
  const int m0 = wave * 16;
  const int lr = lane & 15;
  const int kg = lane >> 4;

  constexpr int NT = N / 16;
  v4f acc[NT];
#pragma unroll
  for (int i = 0; i < NT; ++i) acc[i] = (v4f)(0.f);

#pragma unroll
  for (int ks = 0; ks < 4; ++ks) {
    const int k0 = ks * 32 + kg * 8;
    v8s a = *(const v8s*)&sA[(m0 + lr) * KP + k0];
#pragma unroll
    for (int nt = 0; nt < NT; ++nt) {
      v8s b = *(const v8s*)&sB[(nt * 16 + lr) * KP + k0];
      acc[nt] = __builtin_amdgcn_mfma_f32_16x16x32_bf16(a, b, acc[nt], 0, 0, 0);
    }
  }

#pragma unroll
  for (int nt = 0; nt < NT; ++nt) {
#pragma unroll
    for (int i = 0; i < 4; ++i) {
      int gr = row0 + m0 + kg * 4 + i;
      if (gr < nrows)
        out[(long)gr * N + nt * 16 + lr] = (unsigned short)bf16rne(acc[nt][i]);
    }
  }
}

// ---------------------------------------------------------------------------
// FUSED layer-1 aggregation + layer-2 GEMM.
// Block = 256 threads / 64 nodes. Each wave aggregates 16 consecutive nodes
// (half-wave per edge, 2 edges/VMEM-inst), writes h1 rows (bf16, identical
// rounding as before) to LDS, then runs its 16x64 MFMA tile vs LDS-staged Wt2.
// No block barrier between agg and MFMA: each wave reads only its own sH rows.
__global__ __launch_bounds__(256) void agg128_gemm2_kernel(
    const int* __restrict__ row_ptr, const int* __restrict__ csr_src,
    const float* __restrict__ dinv, const unsigned* __restrict__ hw,  // hw1 [N][64] u32
    const float* __restrict__ bias,                                   // b1
    const unsigned short* __restrict__ Wt2,                           // [64][128] bf16
    unsigned short* __restrict__ hw2) {                               // [N][64] bf16
  constexpr int KP = 136;
  __shared__ unsigned short sH[64 * KP];
  __shared__ unsigned short sB[64 * KP];

  const int t = threadIdx.x;
  const int n0 = blockIdx.x * 64;

  // Stage Wt2 (64 rows x 16 chunks of 16B)
  for (int i = t; i < 64 * 16; i += 256) {
    int r = i >> 4, ch = i & 15;
    *(uint4*)&sB[r * KP + ch * 8] = *(const uint4*)&Wt2[(long)r * 128 + ch * 8];
  }
  __syncthreads();  // sB ready; sH is per-wave private

  const int wave = t >> 6, lane = t & 63;
  const int half = lane >> 5;
  const int lc = lane & 31;        // channel quad: ch 4lc..4lc+3

  for (int r = wave * 16; r < wave * 16 + 16; ++r) {
    const int n = n0 + r;
    float o0 = 0.f, o1 = 0.f, o2 = 0.f, o3 = 0.f;
    if (n < N_NODES) {
      const int start = row_ptr[n];
      const int deg = row_ptr[n + 1] - start;
      const int np = (deg + 1) >> 1;
      float a0 = 0.f, a1 = 0.f, a2 = 0.f, a3 = 0.f;

#define LS(i, pp) { int tt = 2 * (pp) + half; int cl = tt < deg ? tt : deg - 1; \
                    s##i = csr_src[start + cl]; m##i = (tt < deg) ? 1.f : 0.f; }
      int s0, s1, s2, s3;
      float m0, m1, m2, m3;
      if (np > 0) { LS(0, 0) LS(1, 1) LS(2, 2) LS(3, 3) }
      for (int p = 0; p < np; p += 4) {
        int q0 = s0, q1 = s1, q2 = s2, q3 = s3;
        float f0 = m0, f1 = m1, f2 = m2, f3 = m3;
        int pn = p + 4;
        if (pn < np) { LS(0, pn) LS(1, pn + 1) LS(2, pn + 2) LS(3, pn + 3) }
        float w0 = dinv[q0] * f0;
        float w1 = dinv[q1] * f1;
        float w2 = dinv[q2] * f2;
        float w3 = dinv[q3] * f3;
        uint2 u0 = *(const uint2*)&hw[(long)q0 * 64 + 2 * lc];
        uint2 u1 = *(const uint2*)&hw[(long)q1 * 64 + 2 * lc];
        uint2 u2 = *(const uint2*)&hw[(long)q2 * 64 + 2 * lc];
        uint2 u3 = *(const uint2*)&hw[(long)q3 * 64 + 2 * lc];
        a0 = fmaf(bflo_to_f(u0.x), w0, a0); a1 = fmaf(bfhi_to_f(u0.x), w0, a1);
        a2 = fmaf(bflo_to_f(u0.y), w0, a2); a3 = fmaf(bfhi_to_f(u0.y), w0, a3);
        a0 = fmaf(bflo_to_f(u1.x), w1, a0); a1 = fmaf(bfhi_to_f(u1.x), w1, a1);
        a2 = fmaf(bflo_to_f(u1.y), w1, a2); a3 = fmaf(bfhi_to_f(u1.y), w1, a3);
        a0 = fmaf(bflo_to_f(u2.x), w2, a0); a1 = fmaf(bfhi_to_f(u2.x), w2, a1);
        a2 = fmaf(bflo_to_f(u2.y), w2, a2); a3 = fmaf(bfhi_to_f(u2.y), w2, a3);
        a0 = fmaf(bflo_to_f(u3.x), w3, a0); a1 = fmaf(bfhi_to_f(u3.x), w3, a1);
        a2 = fmaf(bflo_to_f(u3.y), w3, a2); a3 = fmaf(bfhi_to_f(u3.y), w3, a3);
      }
#undef LS

      a0 += __shfl_xor(a0, 32);
      a1 += __shfl_xor(a1, 32);
      a2 += __shfl_xor(a2, 32);
      a3 += __shfl_xor(a3, 32);

      float dn = dinv[n];
      float sn = dn * dn;
      uint2 uh = *(const uint2*)&hw[(long)n * 64 + 2 * lc];
      float4 bb = *(const float4*)&bias[4 * lc];
      o0 = fmaxf(fmaf(bflo_to_f(uh.x), sn, a0 * dn) + bb.x, 0.f);
      o1 = fmaxf(fmaf(bfhi_to_f(uh.x), sn, a1 * dn) + bb.y, 0.f);
      o2 = fmaxf(fmaf(bflo_to_f(uh.y), sn, a2 * dn) + bb.z, 0.f);
      o3 = fmaxf(fmaf(bfhi_to_f(uh.y), sn, a3 * dn) + bb.w, 0.f);
    }
    if (half == 0) {
      uint2 pz;
      pz.x = pack2bf(o0, o1);
      pz.y = pack2bf(o2, o3);
      *(uint2*)&sH[r * KP + 4 * lc] = pz;
    }
  }

  // MFMA: each wave multiplies its own 16 h1 rows by Wt2 (sB)
  const int m0 = wave * 16;
  const int lr = lane & 15;
  const int kg = lane >> 4;
  v4f acc[4];
#pragma unroll
  for (int i = 0; i < 4; ++i) acc[i] = (v4f)(0.f);
#pragma unroll
  for (int ks = 0; ks < 4; ++ks) {
    const int k0 = ks * 32 + kg * 8;
    v8s a = *(const v8s*)&sH[(m0 + lr) * KP + k0];
#pragma unroll
    for (int nt = 0; nt < 4; ++nt) {
      v8s b = *(const v8s*)&sB[(nt * 16 + lr) * KP + k0];
      acc[nt] = __builtin_amdgcn_mfma_f32_16x16x32_bf16(a, b, acc[nt], 0, 0, 0);
    }
  }
#pragma unroll
  for (int nt = 0; nt < 4; ++nt) {
#pragma unroll
    for (int i = 0; i < 4; ++i) {
      int gr = n0 + m0 + kg * 4 + i;
      if (gr < N_NODES)
        hw2[(long)gr * 64 + nt * 16 + lr] = (unsigned short)bf16rne(acc[nt][i]);
    }
  }
}

// ---------------------------------------------------------------------------
// Layer-2 aggregation: lane handles 2 channels (u32 = 2 bf16); fp32 output.
__global__ __launch_bounds__(256) void agg64_kernel(
    const int* __restrict__ row_ptr, const int* __restrict__ csr_src,
    const float* __restrict__ dinv, const unsigned* __restrict__ hw,  // [N][32] u32
    const float* __restrict__ bias, float* __restrict__ out) {
  int n = (blockIdx.x * 256 + threadIdx.x) >> 6;
  int lane = threadIdx.x & 63;
  if (n >= N_NODES) return;
  const int half = lane >> 5;
  const int lc = lane & 31;        // channel pair: ch 2lc, 2lc+1
  const int start = row_ptr[n];
  const int deg = row_ptr[n + 1] - start;
  const int np = (deg + 1) >> 1;

  float a0 = 0.f, a1 = 0.f;

#define LS(i, pp) { int tt = 2 * (pp) + half; int cl = tt < deg ? tt : deg - 1; \
                    s##i = csr_src[start + cl]; m##i = (tt < deg) ? 1.f : 0.f; }
  int s0, s1, s2, s3;
  float m0, m1, m2, m3;
  if (np > 0) { LS(0, 0) LS(1, 1) LS(2, 2) LS(3, 3) }
  for (int p = 0; p < np; p += 4) {
    int q0 = s0, q1 = s1, q2 = s2, q3 = s3;
    float f0 = m0, f1 = m1, f2 = m2, f3 = m3;
    int pn = p + 4;
    if (pn < np) { LS(0, pn) LS(1, pn + 1) LS(2, pn + 2) LS(3, pn + 3) }
    float w0 = dinv[q0] * f0;
    float w1 = dinv[q1] * f1;
    float w2 = dinv[q2] * f2;
    float w3 = dinv[q3] * f3;
    unsigned u0 = hw[(long)q0 * 32 + lc];
    unsigned u1 = hw[(long)q1 * 32 + lc];
    unsigned u2 = hw[(long)q2 * 32 + lc];
    unsigned u3 = hw[(long)q3 * 32 + lc];
    a0 = fmaf(bflo_to_f(u0), w0, a0); a1 = fmaf(bfhi_to_f(u0), w0, a1);
    a0 = fmaf(bflo_to_f(u1), w1, a0); a1 = fmaf(bfhi_to_f(u1), w1, a1);
    a0 = fmaf(bflo_to_f(u2), w2, a0); a1 = fmaf(bfhi_to_f(u2), w2, a1);
    a0 = fmaf(bflo_to_f(u3), w3, a0); a1 = fmaf(bfhi_to_f(u3), w3, a1);
  }
#undef LS

  a0 += __shfl_xor(a0, 32);
  a1 += __shfl_xor(a1, 32);

  float dn = dinv[n];
  float sn = dn * dn;
  unsigned uh = hw[(long)n * 32 + lc];
  float2 bb = *(const float2*)&bias[2 * lc];
  float o0 = fmaxf(fmaf(bflo_to_f(uh), sn, a0 * dn) + bb.x, 0.f);
  float o1 = fmaxf(fmaf(bfhi_to_f(uh), sn, a1 * dn) + bb.y, 0.f);
  if (half == 0) {
    *(float2*)&out[(long)n * 64 + 2 * lc] = make_float2(o0, o1);
  }
}

// ---------------------------------------------------------------------------
extern "C" void kernel_launch(void* const* d_in, const int* in_sizes, int n_in,
                              void* d_out, int out_size, void* d_ws, size_t ws_size,
                              hipStream_t stream) {
  const float* x  = (const float*)d_in[0];
  const int*   ei = (const int*)d_in[1];
  const float* W1 = (const float*)d_in[2];
  const float* b1 = (const float*)d_in[3];
  const float* W2 = (const float*)d_in[4];
  const float* b2 = (const float*)d_in[5];
  float* out = (float*)d_out;

  const int* src = ei;             // edge_index[0]
  const int* dst = ei + N_EDGES;   // edge_index[1]

  // Workspace layout (bytes; every chunk is a multiple of 256B)
  char* ws = (char*)d_ws;
  int*   deg     = (int*)ws;                     ws += 50048 * 4;
  float* dinv    = (float*)ws;                   ws += 50048 * 4;
  int*   row_ptr = (int*)ws;                     ws += 50048 * 4;
  int*   bsums   = (int*)ws;                     ws += 64 * 4;
  int*   rank    = (int*)ws;                     ws += (size_t)N_EDGES * 4;
  int*   csr_src = (int*)ws;                     ws += (size_t)N_EDGES * 4;
  unsigned short* Wt1 = (unsigned short*)ws;     ws += 128 * 128 * 2;
  unsigned short* Wt2 = (unsigned short*)ws;     ws += 64 * 128 * 2;
  unsigned short* hw1 = (unsigned short*)ws;     ws += (size_t)N_NODES * 128 * 2;
  unsigned short* hw2 = (unsigned short*)ws;     ws += (size_t)N_NODES * 64 * 2;

  // ---- CSR build + weight conversion ----
  init_kernel<<<49 + 96, 256, 0, stream>>>(deg, W1, W2, Wt1, Wt2);
  hist_kernel<<<(N_EDGES + 255) / 256, 256, 0, stream>>>(dst, deg, rank);
  scan_partial_kernel<<<NB, SCAN_B, 0, stream>>>(deg, bsums, dinv);
  scan_final_kernel<<<NB, SCAN_B, 0, stream>>>(deg, bsums, row_ptr);
  place_kernel<<<(N_EDGES + 255) / 256, 256, 0, stream>>>(src, dst, rank, row_ptr, csr_src);

  // ---- Layer 1 GEMM (x converted to bf16 during staging) ----
  gemm_mfma_kernel<128, true><<<(N_NODES + 63) / 64, 256, 0, stream>>>(
      x, Wt1, hw1, N_NODES);

  // ---- Fused layer-1 aggregation + layer-2 GEMM ----
  agg128_gemm2_kernel<<<(N_NODES + 63) / 64, 256, 0, stream>>>(
      row_ptr, csr_src, dinv, (const unsigned*)hw1, b1, Wt2, hw2);

  // ---- Layer 2 aggregation ----
  agg64_kernel<<<(N_NODES * 64 + 255) / 256, 256, 0, stream>>>(
      row_ptr, csr_src, dinv, (const unsigned*)hw2, b2, out);
}

// Round 9
// 140.345 us; speedup vs baseline: 1.0809x; 1.0809x over previous
//
#include <hip/hip_runtime.h>

// Problem constants (from reference)
#define N_NODES 50000
#define N_EDGES 800000
#define IN_CH   128
#define HID_CH  128
#define OUT_CH  64

#define SCAN_B  1024
#define NB ((N_NODES + SCAN_B - 1) / SCAN_B)   // 49

#define GEMM1_TILES 782          // ceil(50000/64)
#define HIST_BLOCKS 1564

typedef __attribute__((ext_vector_type(8))) short v8s;
typedef __attribute__((ext_vector_type(4))) float v4f;

// ---------------------------------------------------------------------------
// bf16 helpers (RNE)
__device__ __forceinline__ unsigned bf16rne(float f) {
  unsigned u = __float_as_uint(f);
  return (u + 0x7fffu + ((u >> 16) & 1u)) >> 16;
}
__device__ __forceinline__ unsigned pack2bf(float a, float b) {
  return bf16rne(a) | (bf16rne(b) << 16);
}
__device__ __forceinline__ float bfhi_to_f(unsigned u) {   // high ushort
  return __uint_as_float(u & 0xffff0000u);
}
__device__ __forceinline__ float bflo_to_f(unsigned u) {   // low ushort
  return __uint_as_float(u << 16);
}

// ---------------------------------------------------------------------------
// Init: zero deg[] (blocks 0-48) + convert both weight matrices (blocks 49+)
__global__ __launch_bounds__(256) void init_kernel(
    int* __restrict__ deg,
    const float* __restrict__ W1, const float* __restrict__ W2,
    unsigned short* __restrict__ Wt1, unsigned short* __restrict__ Wt2) {
  int b = blockIdx.x;
  if (b < 49) {
    int i = b * 256 + threadIdx.x;
    if (i < 50048 / 4) *(uint4*)&deg[i * 4] = make_uint4(0u, 0u, 0u, 0u);
  } else {
    int idx = (b - 49) * 256 + threadIdx.x;
    if (idx < 128 * 128) {
      int k = idx >> 7, c = idx & 127;
      Wt1[c * 128 + k] = (unsigned short)bf16rne(W1[idx]);
    } else if (idx < 128 * 128 + 128 * 64) {
      int i2 = idx - 128 * 128;
      int k = i2 >> 6, c = i2 & 63;
      Wt2[c * 128 + k] = (unsigned short)bf16rne(W2[i2]);
    }
  }
}

// ---------------------------------------------------------------------------
// MFMA GEMM body: out[nrows x N] bf16 = A[nrows x 128] @ Bt^T, Bt=[N][128] bf16.
// A staged in LDS (fp32->bf16 converted if AFP32); B fragments read straight
// from global (Wt is 16-32KB, L1/L2 resident) -> LDS = 17.4KB only.
template <int N, bool AFP32>
__device__ __forceinline__ void gemm_body(
    int bid, const void* __restrict__ Av, const unsigned short* __restrict__ Bt,
    unsigned short* __restrict__ out, int nrows) {
  constexpr int KP = 136;
  __shared__ unsigned short sA[64 * KP];

  const int row0 = bid * 64;
  const int t = threadIdx.x;

  for (int i = t; i < 64 * 16; i += 256) {
    int r = i >> 4, ch = i & 15;
    uint4 v = make_uint4(0u, 0u, 0u, 0u);
    if (row0 + r < nrows) {
      if constexpr (AFP32) {
        const float* A = (const float*)Av;
        float4 f0 = *(const float4*)&A[(long)(row0 + r) * 128 + ch * 8];
        float4 f1 = *(const float4*)&A[(long)(row0 + r) * 128 + ch * 8 + 4];
        v.x = pack2bf(f0.x, f0.y); v.y = pack2bf(f0.z, f0.w);
        v.z = pack2bf(f1.x, f1.y); v.w = pack2bf(f1.z, f1.w);
      } else {
        const unsigned short* A = (const unsigned short*)Av;
        v = *(const uint4*)&A[(long)(row0 + r) * 128 + ch * 8];
      }
    }
    *(uint4*)&sA[r * KP + ch * 8] = v;
  }
  __syncthreads();

  const int wave = t >> 6, lane = t & 63;
  const int m0 = wave * 16;
  const int lr = lane & 15;
  const int kg = lane >> 4;

  constexpr int NT = N / 16;
  v4f acc[NT];
#pragma unroll
  for (int i = 0; i < NT; ++i) acc[i] = (v4f)(0.f);

#pragma unroll
  for (int ks = 0; ks < 4; ++ks) {
    const int k0 = ks * 32 + kg * 8;
    v8s a = *(const v8s*)&sA[(m0 + lr) * KP + k0];
#pragma unroll
    for (int nt = 0; nt < NT; ++nt) {
      v8s b = *(const v8s*)&Bt[(long)(nt * 16 + lr) * 128 + k0];
      acc[nt] = __builtin_amdgcn_mfma_f32_16x16x32_bf16(a, b, acc[nt], 0, 0, 0);
    }
  }

#pragma unroll
  for (int nt = 0; nt < NT; ++nt) {
#pragma unroll
    for (int i = 0; i < 4; ++i) {
      int gr = row0 + m0 + kg * 4 + i;
      if (gr < nrows)
        out[(long)gr * N + nt * 16 + lr] = (unsigned short)bf16rne(acc[nt][i]);
    }
  }
}

// ---------------------------------------------------------------------------
// Co-scheduled hist (CSR degree histogram + rank) and GEMM1.
// Role interleave keeps both block types resident on every CU:
//   blockIdx%3==0 -> GEMM1 tile; else -> hist (grid-stride over edges).
__global__ __launch_bounds__(256) void hist_gemm1_kernel(
    const int* __restrict__ dst, int* __restrict__ deg, int* __restrict__ rank,
    const float* __restrict__ x, const unsigned short* __restrict__ Wt1,
    unsigned short* __restrict__ hw1) {
  int role = blockIdx.x % 3;
  int gid  = blockIdx.x / 3;
  if (role == 0) {
    if (gid < GEMM1_TILES)
      gemm_body<128, true>(gid, x, Wt1, hw1, N_NODES);
  } else {
    int hb = gid * 2 + (role - 1);     // 0..1563
    for (int e = hb * 256 + (int)threadIdx.x; e < N_EDGES; e += HIST_BLOCKS * 256) {
      rank[e] = atomicAdd(&deg[dst[e]], 1);
    }
  }
}

// ---------------------------------------------------------------------------
// CSR build step 2a: per-chunk sums + dinv (fused; both read deg)
__global__ __launch_bounds__(SCAN_B) void scan_partial_kernel(
    const int* __restrict__ deg, int* __restrict__ bsums, float* __restrict__ dinv) {
  __shared__ int sh[SCAN_B];
  int t = threadIdx.x;
  int g = blockIdx.x * SCAN_B + t;
  int v = (g < N_NODES) ? deg[g] : 0;
  sh[t] = v;
  if (g < N_NODES) dinv[g] = rsqrtf((float)v + 1.0f);
  __syncthreads();
  for (int off = SCAN_B / 2; off > 0; off >>= 1) {
    if (t < off) sh[t] += sh[t + off];
    __syncthreads();
  }
  if (t == 0) bsums[blockIdx.x] = sh[0];
}

// CSR build step 2b: per-chunk exclusive scan; block offset via wave reduce.
__global__ __launch_bounds__(SCAN_B) void scan_final_kernel(
    const int* __restrict__ deg, const int* __restrict__ bsums,
    int* __restrict__ row_ptr) {
  __shared__ int sh[SCAN_B];
  __shared__ int s_off;
  int t = threadIdx.x;
  int g = blockIdx.x * SCAN_B + t;
  int v = (g < N_NODES) ? deg[g] : 0;
  sh[t] = v;
  if (t < 64) {
    int pv = (t < blockIdx.x && t < NB) ? bsums[t] : 0;
#pragma unroll
    for (int off = 32; off > 0; off >>= 1) pv += __shfl_down(pv, off);
    if (t == 0) s_off = pv;
  }
  if (g == 0) row_ptr[N_NODES] = N_EDGES;
  __syncthreads();
  for (int off = 1; off < SCAN_B; off <<= 1) {
    int add = (t >= off) ? sh[t - off] : 0;
    __syncthreads();
    sh[t] += add;
    __syncthreads();
  }
  int excl = sh[t] - v + s_off;
  if (g < N_NODES) row_ptr[g] = excl;
}

// CSR build step 3: place src ids (atomic-free; rank precomputed in hist)
__global__ __launch_bounds__(256) void place_kernel(
    const int* __restrict__ src, const int* __restrict__ dst,
    const int* __restrict__ rank, const int* __restrict__ row_ptr,
    int* __restrict__ csr_src) {
  int e = blockIdx.x * 256 + threadIdx.x;
  if (e < N_EDGES) {
    csr_src[row_ptr[dst[e]] + rank[e]] = src[e];
  }
}

// ---------------------------------------------------------------------------
// Standalone GEMM2 wrapper
__global__ __launch_bounds__(256) void gemm2_kernel(
    const unsigned short* __restrict__ A, const unsigned short* __restrict__ Wt2,
    unsigned short* __restrict__ hw2) {
  gemm_body<64, false>(blockIdx.x, A, Wt2, hw2, N_NODES);
}

// ---------------------------------------------------------------------------
// Layer-1 aggregation, one wave per node, 2 edges per VMEM instruction:
// lanes 0-31 own even edge of a pair, lanes 32-63 the odd edge.
// C=128: lane handles 4 channels (uint2 = 4 bf16). h1 output bf16 packed.
__global__ __launch_bounds__(256) void agg128_kernel(
    const int* __restrict__ row_ptr, const int* __restrict__ csr_src,
    const float* __restrict__ dinv, const unsigned* __restrict__ hw,  // [N][64] u32
    const float* __restrict__ bias, unsigned* __restrict__ h1out) {   // [N][64] u32
  int n = (blockIdx.x * 256 + threadIdx.x) >> 6;
  int lane = threadIdx.x & 63;
  if (n >= N_NODES) return;
  const int half = lane >> 5;      // which edge of the pair
  const int lc = lane & 31;        // channel quad: ch 4lc..4lc+3
  const int start = row_ptr[n];
  const int deg = row_ptr[n + 1] - start;
  const int np = (deg + 1) >> 1;   // pairs (last may be half-valid)

  float a0 = 0.f, a1 = 0.f, a2 = 0.f, a3 = 0.f;

#define LS(i, pp) { int tt = 2 * (pp) + half; int cl = tt < deg ? tt : deg - 1; \
                    s##i = csr_src[start + cl]; m##i = (tt < deg) ? 1.f : 0.f; }
  int s0, s1, s2, s3;
  float m0, m1, m2, m3;
  if (np > 0) { LS(0, 0) LS(1, 1) LS(2, 2) LS(3, 3) }
  for (int p = 0; p < np; p += 4) {
    int q0 = s0, q1 = s1, q2 = s2, q3 = s3;
    float f0 = m0, f1 = m1, f2 = m2, f3 = m3;
    int pn = p + 4;
    if (pn < np) { LS(0, pn) LS(1, pn + 1) LS(2, pn + 2) LS(3, pn + 3) }
    float w0 = dinv[q0] * f0;
    float w1 = dinv[q1] * f1;
    float w2 = dinv[q2] * f2;
    float w3 = dinv[q3] * f3;
    uint2 u0 = *(const uint2*)&hw[(long)q0 * 64 + 2 * lc];
    uint2 u1 = *(const uint2*)&hw[(long)q1 * 64 + 2 * lc];
    uint2 u2 = *(const uint2*)&hw[(long)q2 * 64 + 2 * lc];
    uint2 u3 = *(const uint2*)&hw[(long)q3 * 64 + 2 * lc];
    a0 = fmaf(bflo_to_f(u0.x), w0, a0); a1 = fmaf(bfhi_to_f(u0.x), w0, a1);
    a2 = fmaf(bflo_to_f(u0.y), w0, a2); a3 = fmaf(bfhi_to_f(u0.y), w0, a3);
    a0 = fmaf(bflo_to_f(u1.x), w1, a0); a1 = fmaf(bfhi_to_f(u1.x), w1, a1);
    a2 = fmaf(bflo_to_f(u1.y), w1, a2); a3 = fmaf(bfhi_to_f(u1.y), w1, a3);
    a0 = fmaf(bflo_to_f(u2.x), w2, a0); a1 = fmaf(bfhi_to_f(u2.x), w2, a1);
    a2 = fmaf(bflo_to_f(u2.y), w2, a2); a3 = fmaf(bfhi_to_f(u2.y), w2, a3);
    a0 = fmaf(bflo_to_f(u3.x), w3, a0); a1 = fmaf(bfhi_to_f(u3.x), w3, a1);
    a2 = fmaf(bflo_to_f(u3.y), w3, a2); a3 = fmaf(bfhi_to_f(u3.y), w3, a3);
  }
#undef LS

  a0 += __shfl_xor(a0, 32);
  a1 += __shfl_xor(a1, 32);
  a2 += __shfl_xor(a2, 32);
  a3 += __shfl_xor(a3, 32);

  float dn = dinv[n];
  float sn = dn * dn;
  uint2 uh = *(const uint2*)&hw[(long)n * 64 + 2 * lc];
  float4 bb = *(const float4*)&bias[4 * lc];
  float o0 = fmaxf(fmaf(bflo_to_f(uh.x), sn, a0 * dn) + bb.x, 0.f);
  float o1 = fmaxf(fmaf(bfhi_to_f(uh.x), sn, a1 * dn) + bb.y, 0.f);
  float o2 = fmaxf(fmaf(bflo_to_f(uh.y), sn, a2 * dn) + bb.z, 0.f);
  float o3 = fmaxf(fmaf(bfhi_to_f(uh.y), sn, a3 * dn) + bb.w, 0.f);
  if (half == 0) {
    uint2 pz;
    pz.x = pack2bf(o0, o1);
    pz.y = pack2bf(o2, o3);
    *(uint2*)&h1out[(long)n * 64 + 2 * lc] = pz;
  }
}

// Layer-2 aggregation: lane handles 2 channels (u32 = 2 bf16); fp32 output.
__global__ __launch_bounds__(256) void agg64_kernel(
    const int* __restrict__ row_ptr, const int* __restrict__ csr_src,
    const float* __restrict__ dinv, const unsigned* __restrict__ hw,  // [N][32] u32
    const float* __restrict__ bias, float* __restrict__ out) {
  int n = (blockIdx.x * 256 + threadIdx.x) >> 6;
  int lane = threadIdx.x & 63;
  if (n >= N_NODES) return;
  const int half = lane >> 5;
  const int lc = lane & 31;        // channel pair: ch 2lc, 2lc+1
  const int start = row_ptr[n];
  const int deg = row_ptr[n + 1] - start;
  const int np = (deg + 1) >> 1;

  float a0 = 0.f, a1 = 0.f;

#define LS(i, pp) { int tt = 2 * (pp) + half; int cl = tt < deg ? tt : deg - 1; \
                    s##i = csr_src[start + cl]; m##i = (tt < deg) ? 1.f : 0.f; }
  int s0, s1, s2, s3;
  float m0, m1, m2, m3;
  if (np > 0) { LS(0, 0) LS(1, 1) LS(2, 2) LS(3, 3) }
  for (int p = 0; p < np; p += 4) {
    int q0 = s0, q1 = s1, q2 = s2, q3 = s3;
    float f0 = m0, f1 = m1, f2 = m2, f3 = m3;
    int pn = p + 4;
    if (pn < np) { LS(0, pn) LS(1, pn + 1) LS(2, pn + 2) LS(3, pn + 3) }
    float w0 = dinv[q0] * f0;
    float w1 = dinv[q1] * f1;
    float w2 = dinv[q2] * f2;
    float w3 = dinv[q3] * f3;
    unsigned u0 = hw[(long)q0 * 32 + lc];
    unsigned u1 = hw[(long)q1 * 32 + lc];
    unsigned u2 = hw[(long)q2 * 32 + lc];
    unsigned u3 = hw[(long)q3 * 32 + lc];
    a0 = fmaf(bflo_to_f(u0), w0, a0); a1 = fmaf(bfhi_to_f(u0), w0, a1);
    a0 = fmaf(bflo_to_f(u1), w1, a0); a1 = fmaf(bfhi_to_f(u1), w1, a1);
    a0 = fmaf(bflo_to_f(u2), w2, a0); a1 = fmaf(bfhi_to_f(u2), w2, a1);
    a0 = fmaf(bflo_to_f(u3), w3, a0); a1 = fmaf(bfhi_to_f(u3), w3, a1);
  }
#undef LS

  a0 += __shfl_xor(a0, 32);
  a1 += __shfl_xor(a1, 32);

  float dn = dinv[n];
  float sn = dn * dn;
  unsigned uh = hw[(long)n * 32 + lc];
  float2 bb = *(const float2*)&bias[2 * lc];
  float o0 = fmaxf(fmaf(bflo_to_f(uh), sn, a0 * dn) + bb.x, 0.f);
  float o1 = fmaxf(fmaf(bfhi_to_f(uh), sn, a1 * dn) + bb.y, 0.f);
  if (half == 0) {
    *(float2*)&out[(long)n * 64 + 2 * lc] = make_float2(o0, o1);
  }
}

// ---------------------------------------------------------------------------
extern "C" void kernel_launch(void* const* d_in, const int* in_sizes, int n_in,
                              void* d_out, int out_size, void* d_ws, size_t ws_size,
                              hipStream_t stream) {
  const float* x  = (const float*)d_in[0];
  const int*   ei = (const int*)d_in[1];
  const float* W1 = (const float*)d_in[2];
  const float* b1 = (const float*)d_in[3];
  const float* W2 = (const float*)d_in[4];
  const float* b2 = (const float*)d_in[5];
  float* out = (float*)d_out;

  const int* src = ei;             // edge_index[0]
  const int* dst = ei + N_EDGES;   // edge_index[1]

  // Workspace layout (bytes; every chunk is a multiple of 256B)
  char* ws = (char*)d_ws;
  int*   deg     = (int*)ws;                     ws += 50048 * 4;
  float* dinv    = (float*)ws;                   ws += 50048 * 4;
  int*   row_ptr = (int*)ws;                     ws += 50048 * 4;
  int*   bsums   = (int*)ws;                     ws += 64 * 4;
  int*   rank    = (int*)ws;                     ws += (size_t)N_EDGES * 4;
  int*   csr_src = (int*)ws;                     ws += (size_t)N_EDGES * 4;
  unsigned short* Wt1 = (unsigned short*)ws;     ws += 128 * 128 * 2;
  unsigned short* Wt2 = (unsigned short*)ws;     ws += 64 * 128 * 2;
  unsigned short* hw1 = (unsigned short*)ws;     ws += (size_t)N_NODES * 128 * 2;
  unsigned*       h1  = (unsigned*)ws;           ws += (size_t)N_NODES * 64 * 4;
  unsigned short* hw2 = (unsigned short*)ws;     ws += (size_t)N_NODES * 64 * 2;

  // ---- Init (zero deg + weight conversion) ----
  init_kernel<<<49 + 96, 256, 0, stream>>>(deg, W1, W2, Wt1, Wt2);

  // ---- hist (CSR step 1) co-scheduled with GEMM1 ----
  hist_gemm1_kernel<<<GEMM1_TILES * 3, 256, 0, stream>>>(
      dst, deg, rank, x, Wt1, hw1);

  // ---- CSR scan + place ----
  scan_partial_kernel<<<NB, SCAN_B, 0, stream>>>(deg, bsums, dinv);
  scan_final_kernel<<<NB, SCAN_B, 0, stream>>>(deg, bsums, row_ptr);
  place_kernel<<<(N_EDGES + 255) / 256, 256, 0, stream>>>(src, dst, rank, row_ptr, csr_src);

  // ---- Layer 1 aggregation ----
  agg128_kernel<<<(N_NODES * 64 + 255) / 256, 256, 0, stream>>>(
      row_ptr, csr_src, dinv, (const unsigned*)hw1, b1, h1);

  // ---- Layer 2 GEMM ----
  gemm2_kernel<<<GEMM1_TILES, 256, 0, stream>>>(
      (const unsigned short*)h1, Wt2, hw2);

  // ---- Layer 2 aggregation ----
  agg64_kernel<<<(N_NODES * 64 + 255) / 256, 256, 0, stream>>>(
      row_ptr, csr_src, dinv, (const unsigned*)hw2, b2, out);
}

// Round 10
// 134.037 us; speedup vs baseline: 1.1317x; 1.0471x over previous
//
#include <hip/hip_runtime.h>

// Problem constants (from reference)
#define N_NODES 50000
#define N_EDGES 800000
#define IN_CH   128
#define HID_CH  128
#define OUT_CH  64

#define SCAN_B  1024
#define NB ((N_NODES + SCAN_B - 1) / SCAN_B)   // 49

#define GEMM1_TILES 782          // ceil(50000/64)

typedef __attribute__((ext_vector_type(8))) short v8s;
typedef __attribute__((ext_vector_type(4))) float v4f;

// ---------------------------------------------------------------------------
// bf16 helpers (RNE)
__device__ __forceinline__ unsigned bf16rne(float f) {
  unsigned u = __float_as_uint(f);
  return (u + 0x7fffu + ((u >> 16) & 1u)) >> 16;
}
__device__ __forceinline__ unsigned pack2bf(float a, float b) {
  return bf16rne(a) | (bf16rne(b) << 16);
}
__device__ __forceinline__ float bfhi_to_f(unsigned u) {   // high ushort
  return __uint_as_float(u & 0xffff0000u);
}
__device__ __forceinline__ float bflo_to_f(unsigned u) {   // low ushort
  return __uint_as_float(u << 16);
}

// ---------------------------------------------------------------------------
// Init: zero deg[] (blocks 0-48) + convert both weight matrices (blocks 49+)
__global__ __launch_bounds__(256) void init_kernel(
    int* __restrict__ deg,
    const float* __restrict__ W1, const float* __restrict__ W2,
    unsigned short* __restrict__ Wt1, unsigned short* __restrict__ Wt2) {
  int b = blockIdx.x;
  if (b < 49) {
    int i = b * 256 + threadIdx.x;
    if (i < 50048 / 4) *(uint4*)&deg[i * 4] = make_uint4(0u, 0u, 0u, 0u);
  } else {
    int idx = (b - 49) * 256 + threadIdx.x;
    if (idx < 128 * 128) {
      int k = idx >> 7, c = idx & 127;
      Wt1[c * 128 + k] = (unsigned short)bf16rne(W1[idx]);
    } else if (idx < 128 * 128 + 128 * 64) {
      int i2 = idx - 128 * 128;
      int k = i2 >> 6, c = i2 & 63;
      Wt2[c * 128 + k] = (unsigned short)bf16rne(W2[i2]);
    }
  }
}

// ---------------------------------------------------------------------------
// MFMA GEMM body: out[nrows x N] bf16 = A[nrows x 128] @ Bt^T, Bt=[N][128] bf16.
// A staged in LDS (fp32->bf16 converted if AFP32); B fragments read straight
// from global (Wt is 16-32KB, L1/L2 resident) -> LDS = 17.4KB only.
template <int N, bool AFP32>
__device__ __forceinline__ void gemm_body(
    int bid, const void* __restrict__ Av, const unsigned short* __restrict__ Bt,
    unsigned short* __restrict__ out, int nrows) {
  constexpr int KP = 136;
  __shared__ unsigned short sA[64 * KP];

  const int row0 = bid * 64;
  const int t = threadIdx.x;

  for (int i = t; i < 64 * 16; i += 256) {
    int r = i >> 4, ch = i & 15;
    uint4 v = make_uint4(0u, 0u, 0u, 0u);
    if (row0 + r < nrows) {
      if constexpr (AFP32) {
        const float* A = (const float*)Av;
        float4 f0 = *(const float4*)&A[(long)(row0 + r) * 128 + ch * 8];
        float4 f1 = *(const float4*)&A[(long)(row0 + r) * 128 + ch * 8 + 4];
        v.x = pack2bf(f0.x, f0.y); v.y = pack2bf(f0.z, f0.w);
        v.z = pack2bf(f1.x, f1.y); v.w = pack2bf(f1.z, f1.w);
      } else {
        const unsigned short* A = (const unsigned short*)Av;
        v = *(const uint4*)&A[(long)(row0 + r) * 128 + ch * 8];
      }
    }
    *(uint4*)&sA[r * KP + ch * 8] = v;
  }
  __syncthreads();

  const int wave = t >> 6, lane = t & 63;
  const int m0 = wave * 16;
  const int lr = lane & 15;
  const int kg = lane >> 4;

  constexpr int NT = N / 16;
  v4f acc[NT];
#pragma unroll
  for (int i = 0; i < NT; ++i) acc[i] = (v4f)(0.f);

#pragma unroll
  for (int ks = 0; ks < 4; ++ks) {
    const int k0 = ks * 32 + kg * 8;
    v8s a = *(const v8s*)&sA[(m0 + lr) * KP + k0];
#pragma unroll
    for (int nt = 0; nt < NT; ++nt) {
      v8s b = *(const v8s*)&Bt[(long)(nt * 16 + lr) * 128 + k0];
      acc[nt] = __builtin_amdgcn_mfma_f32_16x16x32_bf16(a, b, acc[nt], 0, 0, 0);
    }
  }

#pragma unroll
  for (int nt = 0; nt < NT; ++nt) {
#pragma unroll
    for (int i = 0; i < 4; ++i) {
      int gr = row0 + m0 + kg * 4 + i;
      if (gr < nrows)
        out[(long)gr * N + nt * 16 + lr] = (unsigned short)bf16rne(acc[nt][i]);
    }
  }
}

// ---------------------------------------------------------------------------
// Co-scheduled hist (CSR degree histogram + rank) and GEMM1.
// blockIdx&1==0 -> GEMM1 tile; ==1 -> hist, 8 edges/thread with all 8
// returning atomics issued back-to-back (8x atomic ILP per thread).
__global__ __launch_bounds__(256) void hist_gemm1_kernel(
    const int* __restrict__ dst, int* __restrict__ deg, int* __restrict__ rank,
    const float* __restrict__ x, const unsigned short* __restrict__ Wt1,
    unsigned short* __restrict__ hw1) {
  int role = blockIdx.x & 1;
  int gid  = blockIdx.x >> 1;
  if (role == 0) {
    gemm_body<128, true>(gid, x, Wt1, hw1, N_NODES);
  } else {
    long base = ((long)gid * 256 + threadIdx.x) * 8;
    if (base < N_EDGES) {
      int4 d0 = *(const int4*)&dst[base];
      int4 d1 = *(const int4*)&dst[base + 4];
      int r0 = atomicAdd(&deg[d0.x], 1);
      int r1 = atomicAdd(&deg[d0.y], 1);
      int r2 = atomicAdd(&deg[d0.z], 1);
      int r3 = atomicAdd(&deg[d0.w], 1);
      int r4 = atomicAdd(&deg[d1.x], 1);
      int r5 = atomicAdd(&deg[d1.y], 1);
      int r6 = atomicAdd(&deg[d1.z], 1);
      int r7 = atomicAdd(&deg[d1.w], 1);
      *(int4*)&rank[base]     = make_int4(r0, r1, r2, r3);
      *(int4*)&rank[base + 4] = make_int4(r4, r5, r6, r7);
    }
  }
}

// ---------------------------------------------------------------------------
// CSR build step 2a: per-chunk sums + dinv (fused; both read deg)
__global__ __launch_bounds__(SCAN_B) void scan_partial_kernel(
    const int* __restrict__ deg, int* __restrict__ bsums, float* __restrict__ dinv) {
  __shared__ int sh[SCAN_B];
  int t = threadIdx.x;
  int g = blockIdx.x * SCAN_B + t;
  int v = (g < N_NODES) ? deg[g] : 0;
  sh[t] = v;
  if (g < N_NODES) dinv[g] = rsqrtf((float)v + 1.0f);
  __syncthreads();
  for (int off = SCAN_B / 2; off > 0; off >>= 1) {
    if (t < off) sh[t] += sh[t + off];
    __syncthreads();
  }
  if (t == 0) bsums[blockIdx.x] = sh[0];
}

// CSR build step 2b: per-chunk exclusive scan; block offset via wave reduce.
__global__ __launch_bounds__(SCAN_B) void scan_final_kernel(
    const int* __restrict__ deg, const int* __restrict__ bsums,
    int* __restrict__ row_ptr) {
  __shared__ int sh[SCAN_B];
  __shared__ int s_off;
  int t = threadIdx.x;
  int g = blockIdx.x * SCAN_B + t;
  int v = (g < N_NODES) ? deg[g] : 0;
  sh[t] = v;
  if (t < 64) {
    int pv = (t < blockIdx.x && t < NB) ? bsums[t] : 0;
#pragma unroll
    for (int off = 32; off > 0; off >>= 1) pv += __shfl_down(pv, off);
    if (t == 0) s_off = pv;
  }
  if (g == 0) row_ptr[N_NODES] = N_EDGES;
  __syncthreads();
  for (int off = 1; off < SCAN_B; off <<= 1) {
    int add = (t >= off) ? sh[t - off] : 0;
    __syncthreads();
    sh[t] += add;
    __syncthreads();
  }
  int excl = sh[t] - v + s_off;
  if (g < N_NODES) row_ptr[g] = excl;
}

// CSR build step 3: place src ids (atomic-free; rank precomputed in hist)
__global__ __launch_bounds__(256) void place_kernel(
    const int* __restrict__ src, const int* __restrict__ dst,
    const int* __restrict__ rank, const int* __restrict__ row_ptr,
    int* __restrict__ csr_src) {
  int e = blockIdx.x * 256 + threadIdx.x;
  if (e < N_EDGES) {
    csr_src[row_ptr[dst[e]] + rank[e]] = src[e];
  }
}

// ---------------------------------------------------------------------------
// Standalone GEMM2 wrapper
__global__ __launch_bounds__(256) void gemm2_kernel(
    const unsigned short* __restrict__ A, const unsigned short* __restrict__ Wt2,
    unsigned short* __restrict__ hw2) {
  gemm_body<64, false>(blockIdx.x, A, Wt2, hw2, N_NODES);
}

// ---------------------------------------------------------------------------
// Layer-1 aggregation, one wave per node, 2 edges per VMEM instruction:
// lanes 0-31 own even edge of a pair, lanes 32-63 the odd edge.
// C=128: lane handles 4 channels (uint2 = 4 bf16). h1 output bf16 packed.
__global__ __launch_bounds__(256) void agg128_kernel(
    const int* __restrict__ row_ptr, const int* __restrict__ csr_src,
    const float* __restrict__ dinv, const unsigned* __restrict__ hw,  // [N][64] u32
    const float* __restrict__ bias, unsigned* __restrict__ h1out) {   // [N][64] u32
  int n = (blockIdx.x * 256 + threadIdx.x) >> 6;
  int lane = threadIdx.x & 63;
  if (n >= N_NODES) return;
  const int half = lane >> 5;      // which edge of the pair
  const int lc = lane & 31;        // channel quad: ch 4lc..4lc+3
  const int start = row_ptr[n];
  const int deg = row_ptr[n + 1] - start;
  const int np = (deg + 1) >> 1;   // pairs (last may be half-valid)

  float a0 = 0.f, a1 = 0.f, a2 = 0.f, a3 = 0.f;

#define LS(i, pp) { int tt = 2 * (pp) + half; int cl = tt < deg ? tt : deg - 1; \
                    s##i = csr_src[start + cl]; m##i = (tt < deg) ? 1.f : 0.f; }
  int s0, s1, s2, s3;
  float m0, m1, m2, m3;
  if (np > 0) { LS(0, 0) LS(1, 1) LS(2, 2) LS(3, 3) }
  for (int p = 0; p < np; p += 4) {
    int q0 = s0, q1 = s1, q2 = s2, q3 = s3;
    float f0 = m0, f1 = m1, f2 = m2, f3 = m3;
    int pn = p + 4;
    if (pn < np) { LS(0, pn) LS(1, pn + 1) LS(2, pn + 2) LS(3, pn + 3) }
    float w0 = dinv[q0] * f0;
    float w1 = dinv[q1] * f1;
    float w2 = dinv[q2] * f2;
    float w3 = dinv[q3] * f3;
    uint2 u0 = *(const uint2*)&hw[(long)q0 * 64 + 2 * lc];
    uint2 u1 = *(const uint2*)&hw[(long)q1 * 64 + 2 * lc];
    uint2 u2 = *(const uint2*)&hw[(long)q2 * 64 + 2 * lc];
    uint2 u3 = *(const uint2*)&hw[(long)q3 * 64 + 2 * lc];
    a0 = fmaf(bflo_to_f(u0.x), w0, a0); a1 = fmaf(bfhi_to_f(u0.x), w0, a1);
    a2 = fmaf(bflo_to_f(u0.y), w0, a2); a3 = fmaf(bfhi_to_f(u0.y), w0, a3);
    a0 = fmaf(bflo_to_f(u1.x), w1, a0); a1 = fmaf(bfhi_to_f(u1.x), w1, a1);
    a2 = fmaf(bflo_to_f(u1.y), w1, a2); a3 = fmaf(bfhi_to_f(u1.y), w1, a3);
    a0 = fmaf(bflo_to_f(u2.x), w2, a0); a1 = fmaf(bfhi_to_f(u2.x), w2, a1);
    a2 = fmaf(bflo_to_f(u2.y), w2, a2); a3 = fmaf(bfhi_to_f(u2.y), w2, a3);
    a0 = fmaf(bflo_to_f(u3.x), w3, a0); a1 = fmaf(bfhi_to_f(u3.x), w3, a1);
    a2 = fmaf(bflo_to_f(u3.y), w3, a2); a3 = fmaf(bfhi_to_f(u3.y), w3, a3);
  }
#undef LS

  a0 += __shfl_xor(a0, 32);
  a1 += __shfl_xor(a1, 32);
  a2 += __shfl_xor(a2, 32);
  a3 += __shfl_xor(a3, 32);

  float dn = dinv[n];
  float sn = dn * dn;
  uint2 uh = *(const uint2*)&hw[(long)n * 64 + 2 * lc];
  float4 bb = *(const float4*)&bias[4 * lc];
  float o0 = fmaxf(fmaf(bflo_to_f(uh.x), sn, a0 * dn) + bb.x, 0.f);
  float o1 = fmaxf(fmaf(bfhi_to_f(uh.x), sn, a1 * dn) + bb.y, 0.f);
  float o2 = fmaxf(fmaf(bflo_to_f(uh.y), sn, a2 * dn) + bb.z, 0.f);
  float o3 = fmaxf(fmaf(bfhi_to_f(uh.y), sn, a3 * dn) + bb.w, 0.f);
  if (half == 0) {
    uint2 pz;
    pz.x = pack2bf(o0, o1);
    pz.y = pack2bf(o2, o3);
    *(uint2*)&h1out[(long)n * 64 + 2 * lc] = pz;
  }
}

// Layer-2 aggregation: lane handles 2 channels (u32 = 2 bf16); fp32 output.
__global__ __launch_bounds__(256) void agg64_kernel(
    const int* __restrict__ row_ptr, const int* __restrict__ csr_src,
    const float* __restrict__ dinv, const unsigned* __restrict__ hw,  // [N][32] u32
    const float* __restrict__ bias, float* __restrict__ out) {
  int n = (blockIdx.x * 256 + threadIdx.x) >> 6;
  int lane = threadIdx.x & 63;
  if (n >= N_NODES) return;
  const int half = lane >> 5;
  const int lc = lane & 31;        // channel pair: ch 2lc, 2lc+1
  const int start = row_ptr[n];
  const int deg = row_ptr[n + 1] - start;
  const int np = (deg + 1) >> 1;

  float a0 = 0.f, a1 = 0.f;

#define LS(i, pp) { int tt = 2 * (pp) + half; int cl = tt < deg ? tt : deg - 1; \
                    s##i = csr_src[start + cl]; m##i = (tt < deg) ? 1.f : 0.f; }
  int s0, s1, s2, s3;
  float m0, m1, m2, m3;
  if (np > 0) { LS(0, 0) LS(1, 1) LS(2, 2) LS(3, 3) }
  for (int p = 0; p < np; p += 4) {
    int q0 = s0, q1 = s1, q2 = s2, q3 = s3;
    float f0 = m0, f1 = m1, f2 = m2, f3 = m3;
    int pn = p + 4;
    if (pn < np) { LS(0, pn) LS(1, pn + 1) LS(2, pn + 2) LS(3, pn + 3) }
    float w0 = dinv[q0] * f0;
    float w1 = dinv[q1] * f1;
    float w2 = dinv[q2] * f2;
    float w3 = dinv[q3] * f3;
    unsigned u0 = hw[(long)q0 * 32 + lc];
    unsigned u1 = hw[(long)q1 * 32 + lc];
    unsigned u2 = hw[(long)q2 * 32 + lc];
    unsigned u3 = hw[(long)q3 * 32 + lc];
    a0 = fmaf(bflo_to_f(u0), w0, a0); a1 = fmaf(bfhi_to_f(u0), w0, a1);
    a0 = fmaf(bflo_to_f(u1), w1, a0); a1 = fmaf(bfhi_to_f(u1), w1, a1);
    a0 = fmaf(bflo_to_f(u2), w2, a0); a1 = fmaf(bfhi_to_f(u2), w2, a1);
    a0 = fmaf(bflo_to_f(u3), w3, a0); a1 = fmaf(bfhi_to_f(u3), w3, a1);
  }
#undef LS

  a0 += __shfl_xor(a0, 32);
  a1 += __shfl_xor(a1, 32);

  float dn = dinv[n];
  float sn = dn * dn;
  unsigned uh = hw[(long)n * 32 + lc];
  float2 bb = *(const float2*)&bias[2 * lc];
  float o0 = fmaxf(fmaf(bflo_to_f(uh), sn, a0 * dn) + bb.x, 0.f);
  float o1 = fmaxf(fmaf(bfhi_to_f(uh), sn, a1 * dn) + bb.y, 0.f);
  if (half == 0) {
    *(float2*)&out[(long)n * 64 + 2 * lc] = make_float2(o0, o1);
  }
}

// ---------------------------------------------------------------------------
extern "C" void kernel_launch(void* const* d_in, const int* in_sizes, int n_in,
                              void* d_out, int out_size, void* d_ws, size_t ws_size,
                              hipStream_t stream) {
  const float* x  = (const float*)d_in[0];
  const int*   ei = (const int*)d_in[1];
  const float* W1 = (const float*)d_in[2];
  const float* b1 = (const float*)d_in[3];
  const float* W2 = (const float*)d_in[4];
  const float* b2 = (const float*)d_in[5];
  float* out = (float*)d_out;

  const int* src = ei;             // edge_index[0]
  const int* dst = ei + N_EDGES;   // edge_index[1]

  // Workspace layout (bytes; every chunk is a multiple of 256B)
  char* ws = (char*)d_ws;
  int*   deg     = (int*)ws;                     ws += 50048 * 4;
  float* dinv    = (float*)ws;                   ws += 50048 * 4;
  int*   row_ptr = (int*)ws;                     ws += 50048 * 4;
  int*   bsums   = (int*)ws;                     ws += 64 * 4;
  int*   rank    = (int*)ws;                     ws += (size_t)N_EDGES * 4;
  int*   csr_src = (int*)ws;                     ws += (size_t)N_EDGES * 4;
  unsigned short* Wt1 = (unsigned short*)ws;     ws += 128 * 128 * 2;
  unsigned short* Wt2 = (unsigned short*)ws;     ws += 64 * 128 * 2;
  unsigned short* hw1 = (unsigned short*)ws;     ws += (size_t)N_NODES * 128 * 2;
  unsigned*       h1  = (unsigned*)ws;           ws += (size_t)N_NODES * 64 * 4;
  unsigned short* hw2 = (unsigned short*)ws;     ws += (size_t)N_NODES * 64 * 2;

  // ---- Init (zero deg + weight conversion) ----
  init_kernel<<<49 + 96, 256, 0, stream>>>(deg, W1, W2, Wt1, Wt2);

  // ---- hist (8 edges/thread, batched atomics) co-scheduled with GEMM1 ----
  hist_gemm1_kernel<<<GEMM1_TILES * 2, 256, 0, stream>>>(
      dst, deg, rank, x, Wt1, hw1);

  // ---- CSR scan + place ----
  scan_partial_kernel<<<NB, SCAN_B, 0, stream>>>(deg, bsums, dinv);
  scan_final_kernel<<<NB, SCAN_B, 0, stream>>>(deg, bsums, row_ptr);
  place_kernel<<<(N_EDGES + 255) / 256, 256, 0, stream>>>(src, dst, rank, row_ptr, csr_src);

  // ---- Layer 1 aggregation ----
  agg128_kernel<<<(N_NODES * 64 + 255) / 256, 256, 0, stream>>>(
      row_ptr, csr_src, dinv, (const unsigned*)hw1, b1, h1);

  // ---- Layer 2 GEMM ----
  gemm2_kernel<<<GEMM1_TILES, 256, 0, stream>>>(
      (const unsigned short*)h1, Wt2, hw2);

  // ---- Layer 2 aggregation ----
  agg64_kernel<<<(N_NODES * 64 + 255) / 256, 256, 0, stream>>>(
      row_ptr, csr_src, dinv, (const unsigned*)hw2, b2, out);
}